// Round 13
// baseline (185.968 us; speedup 1.0000x reference)
//
#include <hip/hip_runtime.h>
#include <hip/hip_bf16.h>
#include <math.h>

// Problem constants (GAT_66907000537778)
#define NNODES 50000
#define NEDGES 800000
#define FIN 256
#define HID 32
#define HEADS 4
#define OUTS 40
#define HIDDEN 128   // HEADS*HID
#define CH 3200      // edges per sort block (250 * 3200 = 800000 exactly)
#define NSB 250      // sort blocks

typedef __bf16 bf16x8 __attribute__((ext_vector_type(8)));
typedef float  f32x4  __attribute__((ext_vector_type(4)));

// ---------------------------------------------------------------------------
// fused prep (weight converts, blocks 0..215) + sort hist (blocks 216..465)
// ---------------------------------------------------------------------------
__global__ __launch_bounds__(256) void k_prep_hist(
    const float* __restrict__ W1, const float* __restrict__ W2,
    const float* __restrict__ W3, __bf16* __restrict__ Wt1,
    __bf16* __restrict__ Wt2, __bf16* __restrict__ Wt3,
    const int* __restrict__ src, const int* __restrict__ dst,
    unsigned* __restrict__ keysA, int* __restrict__ gh, int n) {
    __shared__ int lh[256];
    int b = blockIdx.x, t = threadIdx.x;
    if (b < 128) {                 // W1 [256][128] -> Wt1 [128][256]
        int i = b * 256 + t;
        int k = i >> 7, c = i & 127;
        Wt1[(size_t)c * 256 + k] = (__bf16)W1[i];
    } else if (b < 192) {          // W2 [128][128] -> Wt2 [128][128]
        int i = (b - 128) * 256 + t;
        int k = i >> 7, c = i & 127;
        Wt2[(size_t)c * 128 + k] = (__bf16)W2[i];
    } else if (b < 216) {          // W3 [128][40] -> Wt3 [48][128], rows 40..47 zero
        int i = (b - 192) * 256 + t;
        int c = i >> 7, k = i & 127;
        Wt3[(size_t)c * 128 + k] = (c < 40) ? (__bf16)W3[(size_t)k * 40 + c] : (__bf16)0.f;
    } else {                       // sort stage 1: pack keys + per-(bin,block) hist
        int sb = b - 216;
        lh[t] = 0;
        __syncthreads();
        int i0 = sb * CH, i1 = i0 + CH; if (i1 > n) i1 = n;
        for (int i = i0 + t; i < i1; i += 256) {
            int d = dst[i];
            keysA[i] = ((unsigned)d << 16) | (unsigned)(src[i] & 0xffff);
            atomicAdd(&lh[d >> 8], 1);
        }
        __syncthreads();
        gh[t * NSB + sb] = lh[t];  // bin-major layout
    }
}

// ---------------------------------------------------------------------------
// scans: stage1 per-block excl scan; stage2+3 merged (redundant bsum scan)
// ---------------------------------------------------------------------------
__global__ __launch_bounds__(256) void k_scan1(const int* __restrict__ counts,
                                               int* __restrict__ pre,
                                               int* __restrict__ bsum, int n) {
    __shared__ int ws[4];
    int t = threadIdx.x, b = blockIdx.x, i = b * 256 + t;
    int lane = t & 63, w = t >> 6;
    int v = (i < n) ? counts[i] : 0;
    int x = v;
    #pragma unroll
    for (int off = 1; off < 64; off <<= 1) {
        int tt = __shfl_up(x, off);
        if (lane >= off) x += tt;
    }
    if (lane == 63) ws[w] = x;
    __syncthreads();
    int woff = 0;
    #pragma unroll
    for (int k = 0; k < 4; ++k) woff += (k < w) ? ws[k] : 0;
    int excl = x - v + woff;
    if (i < n) pre[i] = excl;
    if (t == 255) bsum[b] = excl + v;
}

__global__ __launch_bounds__(256) void k_scan3b(int* __restrict__ ghs,
                                                const int* __restrict__ bsum,
                                                int nb, int n) {
    __shared__ int arr[256];
    __shared__ int ws[4];
    int t = threadIdx.x, b = blockIdx.x;
    int lane = t & 63, w = t >> 6;
    int v = (t < nb) ? bsum[t] : 0;
    int x = v;
    #pragma unroll
    for (int off = 1; off < 64; off <<= 1) {
        int tt = __shfl_up(x, off);
        if (lane >= off) x += tt;
    }
    if (lane == 63) ws[w] = x;
    __syncthreads();
    int woff = 0;
    #pragma unroll
    for (int k = 0; k < 4; ++k) woff += (k < w) ? ws[k] : 0;
    arr[t] = x - v + woff;   // exclusive prefix of bsum
    __syncthreads();
    int sx = arr[b];
    int i = b * 256 + t;
    if (i < n) ghs[i] += sx;
}

// scatter into contiguous bucket regions (order within bucket free)
__global__ __launch_bounds__(256) void rs_scatter1(
    const unsigned* __restrict__ keysA, unsigned* __restrict__ keysB,
    const int* __restrict__ ghs, int n) {
    __shared__ int base[256];
    int t = threadIdx.x, b = blockIdx.x;
    base[t] = ghs[t * NSB + b];
    __syncthreads();
    int i0 = b * CH, i1 = i0 + CH; if (i1 > n) i1 = n;
    for (int i = i0 + t; i < i1; i += 256) {
        unsigned v = keysA[i];
        int bin = v >> 24;           // dst >> 8
        int pos = atomicAdd(&base[bin], 1);
        keysB[pos] = v;
    }
}

// per-bucket counting sort -> row_ptr + csr16 (one block per bucket)
__global__ __launch_bounds__(256) void rs_bucket(
    const unsigned* __restrict__ keysB, const int* __restrict__ ghs,
    ushort* __restrict__ csr16, int* __restrict__ rp, int n) {
    __shared__ int cnt[256];
    __shared__ int ws[4];
    int t = threadIdx.x, hb = blockIdx.x;
    int start = ghs[hb * NSB];
    int end = (hb == 255) ? n : ghs[(hb + 1) * NSB];
    cnt[t] = 0;
    __syncthreads();
    for (int i = start + t; i < end; i += 256)
        atomicAdd(&cnt[(keysB[i] >> 16) & 255], 1);
    __syncthreads();
    int lane = t & 63, w = t >> 6;
    int v = cnt[t];
    int x = v;
    #pragma unroll
    for (int off = 1; off < 64; off <<= 1) {
        int tt = __shfl_up(x, off);
        if (lane >= off) x += tt;
    }
    if (lane == 63) ws[w] = x;
    __syncthreads();
    int woff = 0;
    #pragma unroll
    for (int k = 0; k < 4; ++k) woff += (k < w) ? ws[k] : 0;
    int excl = x - v + woff;
    int node = hb * 256 + t;
    if (node <= NNODES) rp[node] = start + excl;
    __syncthreads();
    cnt[t] = excl;
    __syncthreads();
    for (int i = start + t; i < end; i += 256) {
        unsigned v2 = keysB[i];
        int j = (v2 >> 16) & 255;
        int pos = start + atomicAdd(&cnt[j], 1);
        csr16[pos] = (ushort)(v2 & 0xffffu);
    }
}

// ---------------------------------------------------------------------------
// MFMA bf16 GEMM, N=128, fused attention-score epilogue.
// AF32: A is fp32 (converted during LDS staging); else bf16.
// ---------------------------------------------------------------------------
template<bool AF32>
__global__ __launch_bounds__(256) void gemm_mfma_128(
    const void* __restrict__ Av, const __bf16* __restrict__ Wt,
    const float* __restrict__ al, const float* __restrict__ ar,
    __bf16* __restrict__ z, float* __restrict__ el, float* __restrict__ er,
    int M, int K)
{
    __shared__ alignas(16) __bf16 As[64 * 40];
    __shared__ alignas(16) __bf16 Bs[128 * 40];
    int tid = threadIdx.x;
    int wv = tid >> 6, l = tid & 63;
    int lr = l & 15, lk = l >> 4;
    int m0 = blockIdx.x * 64;
    f32x4 acc[8];
    f32x4 zero4 = {0.f, 0.f, 0.f, 0.f};
    #pragma unroll
    for (int nt = 0; nt < 8; ++nt) acc[nt] = zero4;

    int ar_ = tid >> 2, aq = tid & 3;
    for (int k0 = 0; k0 < K; k0 += 32) {
        {   // A tile: 64 x 32 bf16
            int m = m0 + ar_;
            if constexpr (AF32) {
                const float* A = (const float*)Av;
                __bf16 t8[8] = {};
                if (m < M) {
                    const float4* p = reinterpret_cast<const float4*>(&A[(size_t)m * K + k0 + aq * 8]);
                    float4 a = p[0], b = p[1];
                    t8[0] = (__bf16)a.x; t8[1] = (__bf16)a.y; t8[2] = (__bf16)a.z; t8[3] = (__bf16)a.w;
                    t8[4] = (__bf16)b.x; t8[5] = (__bf16)b.y; t8[6] = (__bf16)b.z; t8[7] = (__bf16)b.w;
                }
                *reinterpret_cast<uint4*>(&As[ar_ * 40 + aq * 8]) = *reinterpret_cast<uint4*>(t8);
            } else {
                const __bf16* A = (const __bf16*)Av;
                uint4 av = make_uint4(0, 0, 0, 0);
                if (m < M) av = *reinterpret_cast<const uint4*>(&A[(size_t)m * K + k0 + aq * 8]);
                *reinterpret_cast<uint4*>(&As[ar_ * 40 + aq * 8]) = av;
            }
        }
        {   // B tile: Wt rows (col-major W): 128 x 32 bf16
            #pragma unroll
            for (int t = 0; t < 2; ++t) {
                int cid = tid + t * 256;
                int c = cid >> 2, q = cid & 3;
                *reinterpret_cast<uint4*>(&Bs[c * 40 + q * 8]) =
                    *reinterpret_cast<const uint4*>(&Wt[(size_t)c * K + k0 + q * 8]);
            }
        }
        __syncthreads();
        bf16x8 af = *reinterpret_cast<const bf16x8*>(&As[(wv * 16 + lr) * 40 + lk * 8]);
        #pragma unroll
        for (int nt = 0; nt < 8; ++nt) {
            bf16x8 bfr = *reinterpret_cast<const bf16x8*>(&Bs[(nt * 16 + lr) * 40 + lk * 8]);
            acc[nt] = __builtin_amdgcn_mfma_f32_16x16x32_bf16(af, bfr, acc[nt], 0, 0, 0);
        }
        __syncthreads();
    }

    float alv[8], arv[8];
    #pragma unroll
    for (int nt = 0; nt < 8; ++nt) {
        alv[nt] = al[nt * 16 + lr];
        arv[nt] = ar[nt * 16 + lr];
    }
    #pragma unroll
    for (int r = 0; r < 4; ++r) {
        int m = m0 + wv * 16 + lk * 4 + r;   // C/D: row=(lane>>4)*4+reg, col=lane&15
        float pel[4], per_[4];
        #pragma unroll
        for (int h = 0; h < 4; ++h) {
            pel[h]  = acc[2 * h][r] * alv[2 * h] + acc[2 * h + 1][r] * alv[2 * h + 1];
            per_[h] = acc[2 * h][r] * arv[2 * h] + acc[2 * h + 1][r] * arv[2 * h + 1];
        }
        #pragma unroll
        for (int mk = 1; mk < 16; mk <<= 1) {
            #pragma unroll
            for (int h = 0; h < 4; ++h) {
                pel[h]  += __shfl_xor(pel[h], mk);
                per_[h] += __shfl_xor(per_[h], mk);
            }
        }
        if (m < M) {
            #pragma unroll
            for (int nt = 0; nt < 8; ++nt)
                z[(size_t)m * 128 + nt * 16 + lr] = (__bf16)acc[nt][r];
            if (lr == 0) {
                #pragma unroll
                for (int h = 0; h < 4; ++h) {
                    el[m * 4 + h] = pel[h];
                    er[m * 4 + h] = per_[h];
                }
            }
        }
    }
}

// ---------------------------------------------------------------------------
// layer-3 MFMA GEMM: z40[M,40(pad64)] = A[M,128] * W3[128,40], fused el3/er3.
// ---------------------------------------------------------------------------
__global__ __launch_bounds__(256) void gemm40_mfma(
    const __bf16* __restrict__ A, const __bf16* __restrict__ Wt3,
    const float* __restrict__ al, const float* __restrict__ arr,
    __bf16* __restrict__ z40, float* __restrict__ el3, float* __restrict__ er3,
    int M)
{
    __shared__ alignas(16) __bf16 As[64 * 40];
    __shared__ alignas(16) __bf16 Bs[48 * 40];
    int tid = threadIdx.x;
    int wv = tid >> 6, l = tid & 63;
    int lr = l & 15, lk = l >> 4;
    int m0 = blockIdx.x * 64;
    f32x4 acc[3];
    f32x4 zero4 = {0.f, 0.f, 0.f, 0.f};
    #pragma unroll
    for (int nt = 0; nt < 3; ++nt) acc[nt] = zero4;

    int ar_ = tid >> 2, aq = tid & 3;
    for (int k0 = 0; k0 < 128; k0 += 32) {
        {
            int m = m0 + ar_;
            uint4 av = make_uint4(0, 0, 0, 0);
            if (m < M) av = *reinterpret_cast<const uint4*>(&A[(size_t)m * 128 + k0 + aq * 8]);
            *reinterpret_cast<uint4*>(&As[ar_ * 40 + aq * 8]) = av;
        }
        if (tid < 192) {
            int c = tid >> 2, q = tid & 3;
            *reinterpret_cast<uint4*>(&Bs[c * 40 + q * 8]) =
                *reinterpret_cast<const uint4*>(&Wt3[(size_t)c * 128 + k0 + q * 8]);
        }
        __syncthreads();
        bf16x8 af = *reinterpret_cast<const bf16x8*>(&As[(wv * 16 + lr) * 40 + lk * 8]);
        #pragma unroll
        for (int nt = 0; nt < 3; ++nt) {
            bf16x8 bfr = *reinterpret_cast<const bf16x8*>(&Bs[(nt * 16 + lr) * 40 + lk * 8]);
            acc[nt] = __builtin_amdgcn_mfma_f32_16x16x32_bf16(af, bfr, acc[nt], 0, 0, 0);
        }
        __syncthreads();
    }

    float alv[3], arv[3];
    #pragma unroll
    for (int nt = 0; nt < 3; ++nt) {
        int col = nt * 16 + lr;
        alv[nt] = (col < 40) ? al[col] : 0.f;
        arv[nt] = (col < 40) ? arr[col] : 0.f;
    }
    #pragma unroll
    for (int r = 0; r < 4; ++r) {
        int m = m0 + wv * 16 + lk * 4 + r;
        float pel = acc[0][r] * alv[0] + acc[1][r] * alv[1] + acc[2][r] * alv[2];
        float per_ = acc[0][r] * arv[0] + acc[1][r] * arv[1] + acc[2][r] * arv[2];
        #pragma unroll
        for (int mk = 1; mk < 16; mk <<= 1) {
            pel  += __shfl_xor(pel, mk);
            per_ += __shfl_xor(per_, mk);
        }
        if (m < M) {
            #pragma unroll
            for (int nt = 0; nt < 3; ++nt) {
                int col = nt * 16 + lr;
                if (col < 40) z40[(size_t)m * 64 + col] = (__bf16)acc[nt][r];
            }
            if (lr == 0) { el3[m] = pel; er3[m] = per_; }
        }
    }
}

// ---------------------------------------------------------------------------
// edge-softmax + aggregation, layers 1-2 (H=4, F=32). One wave per node.
// EARLY-ISSUE: all 16 z-gathers issue right after the cs load (sidx spread
// via __shfl/bpermute, no LDS round-trip); the el-gather + softmax runs
// under the z-load latency. Arithmetic identical to the serial version.
// ---------------------------------------------------------------------------
__global__ __launch_bounds__(256) void gat_agg128w(
    const __bf16* __restrict__ z, const float* __restrict__ el,
    const float* __restrict__ er, const int* __restrict__ rp,
    const ushort* __restrict__ cs, const float* __restrict__ bias,
    __bf16* __restrict__ hout, int n_nodes)
{
    int tid = threadIdx.x, w = tid >> 6, t = tid & 63;
    int g = t >> 4, j = t & 15;
    int base16 = t & 48;   // g*16
    int nd = blockIdx.x * 4 + w;
    if (nd >= n_nodes) return;
    int beg = rp[nd], end = rp[nd + 1];
    float erv = er[nd * 4 + g];
    float m = -3.0e38f, s = 0.f, acc0 = 0.f, acc1 = 0.f;
    const int eoff = g * 32 + 2 * j;

    for (int c0 = beg; c0 < end; c0 += 16) {
        int ch = end - c0; if (ch > 16) ch = 16;
        // coalesced edge-src load (pads -> row 0)
        int sidx = (j < ch) ? (int)cs[c0 + j] : 0;
        // ---- issue ALL 16 z gathers NOW (addresses need only sidx) ----
        unsigned ld[16];
        #pragma unroll
        for (int u = 0; u < 16; ++u) {
            int su = __shfl(sidx, base16 | u);
            ld[u] = *reinterpret_cast<const unsigned*>(&z[((size_t)su << 7) + eoff]);
        }
        // ---- softmax phase (overlaps z-load latency) ----
        float e = -3.0e38f;
        if (j < ch) {
            float ev = el[sidx * 4 + g] + erv;
            e = (ev > 0.f) ? ev : 0.2f * ev;
        }
        float cm = e;
        #pragma unroll
        for (int mk = 8; mk; mk >>= 1) cm = fmaxf(cm, __shfl_xor(cm, mk));
        float nm = fmaxf(m, cm);
        float p = (j < ch) ? __expf(e - nm) : 0.f;
        float ps = p;
        #pragma unroll
        for (int mk = 8; mk; mk >>= 1) ps += __shfl_xor(ps, mk);
        float so = __expf(m - nm);
        s = s * so + ps;
        m = nm;
        acc0 *= so; acc1 *= so;
        // ---- consume ----
        #pragma unroll
        for (int u = 0; u < 16; ++u) {
            float pu = __shfl(p, base16 | u);
            float z0 = __uint_as_float(ld[u] << 16);
            float z1 = __uint_as_float(ld[u] & 0xffff0000u);
            acc0 += pu * z0;
            acc1 += pu * z1;
        }
    }
    float o0 = (end > beg) ? acc0 / s : 0.f;
    float o1 = (end > beg) ? acc1 / s : 0.f;
    o0 = fmaxf(o0 + bias[eoff], 0.f);       // relu (layers 1-2)
    o1 = fmaxf(o1 + bias[eoff + 1], 0.f);
    __bf16 t2[2] = {(__bf16)o0, (__bf16)o1};
    *reinterpret_cast<unsigned*>(&hout[(size_t)nd * 128 + eoff]) = *reinterpret_cast<unsigned*>(t2);
}

// ---------------------------------------------------------------------------
// layer-3 aggregation: 1 node per wave, early-issue + ping-pong gathers,
// + bias + log_softmax
// ---------------------------------------------------------------------------
__device__ __forceinline__ void agg40_issue8(const __bf16* __restrict__ z40,
                                             const unsigned* __restrict__ offRow,
                                             int kk, int lane, ushort* ld) {
    #pragma unroll
    for (int u = 0; u < 8; ++u)
        ld[u] = *reinterpret_cast<const ushort*>(&z40[(size_t)offRow[kk + u] + lane]);
}
__device__ __forceinline__ void agg40_consume8(const unsigned* __restrict__ pRow,
                                               int kk, const ushort* ld, float& acc) {
    #pragma unroll
    for (int u = 0; u < 8; ++u) {
        float pu = __uint_as_float(pRow[kk + u]);
        float zv = __uint_as_float(((unsigned)ld[u]) << 16);
        acc += pu * zv;
    }
}

__global__ __launch_bounds__(256) void gat_agg40c(
    const __bf16* __restrict__ z40, const float* __restrict__ el3,
    const float* __restrict__ er3, const int* __restrict__ rp,
    const ushort* __restrict__ cs, const float* __restrict__ bias,
    float* __restrict__ out, int n_nodes)
{
    __shared__ unsigned shOff[4][64];
    __shared__ unsigned shP[4][64];
    int tid = threadIdx.x, wid = tid >> 6, lane = tid & 63;
    int nd = blockIdx.x * 4 + wid;
    if (nd >= n_nodes) return;
    bool act = lane < 40;
    int beg = rp[nd], end = rp[nd + 1];
    float erv = er3[nd];
    float m = -3.0e38f, s = 0.f, acc = 0.f;

    for (int c0 = beg; c0 < end; c0 += 64) {
        int ch = end - c0; if (ch > 64) ch = 64;
        int chp = (ch + 7) & ~7;
        int sidx = (lane < ch) ? (int)cs[c0 + lane] : 0;
        shOff[wid][lane] = (unsigned)(sidx << 6);
        // (same-wave LDS visibility; no barrier)
        ushort ldA[8], ldB[8];
        agg40_issue8(z40, shOff[wid], 0, lane, ldA);   // batch 0 in flight
        // ---- softmax (overlaps batch-0 latency) ----
        float e = -3.0e38f;
        if (lane < ch) {
            float ev = el3[sidx] + erv;
            e = (ev > 0.f) ? ev : 0.2f * ev;
        }
        float cm = e;
        #pragma unroll
        for (int mk = 32; mk; mk >>= 1) cm = fmaxf(cm, __shfl_xor(cm, mk));
        float nm = fmaxf(m, cm);
        float p = (lane < ch) ? __expf(e - nm) : 0.f;
        float ps = p;
        #pragma unroll
        for (int mk = 32; mk; mk >>= 1) ps += __shfl_xor(ps, mk);
        float so = __expf(m - nm);
        s = s * so + ps;
        acc *= so;
        m = nm;
        shP[wid][lane] = __float_as_uint(p);
        // ---- ping-pong consume (issue-ahead one batch) ----
        if (8 < chp)  agg40_issue8(z40, shOff[wid], 8, lane, ldB);
        agg40_consume8(shP[wid], 0, ldA, acc);
        if (8 < chp) {
            if (16 < chp) agg40_issue8(z40, shOff[wid], 16, lane, ldA);
            agg40_consume8(shP[wid], 8, ldB, acc);
        }
        if (16 < chp) {
            if (24 < chp) agg40_issue8(z40, shOff[wid], 24, lane, ldB);
            agg40_consume8(shP[wid], 16, ldA, acc);
        }
        if (24 < chp) {
            if (32 < chp) agg40_issue8(z40, shOff[wid], 32, lane, ldA);
            agg40_consume8(shP[wid], 24, ldB, acc);
        }
        if (32 < chp) {
            if (40 < chp) agg40_issue8(z40, shOff[wid], 40, lane, ldB);
            agg40_consume8(shP[wid], 32, ldA, acc);
        }
        if (40 < chp) {
            if (48 < chp) agg40_issue8(z40, shOff[wid], 48, lane, ldA);
            agg40_consume8(shP[wid], 40, ldB, acc);
        }
        if (48 < chp) {
            if (56 < chp) agg40_issue8(z40, shOff[wid], 56, lane, ldB);
            agg40_consume8(shP[wid], 48, ldA, acc);
        }
        if (56 < chp) agg40_consume8(shP[wid], 56, ldB, acc);
    }
    float o = (end > beg) ? acc / s : 0.f;
    o += act ? bias[lane] : 0.f;
    float v = act ? o : -3.0e38f;
    float mx = v;
    #pragma unroll
    for (int off = 32; off > 0; off >>= 1) mx = fmaxf(mx, __shfl_xor(mx, off));
    float p2 = act ? __expf(o - mx) : 0.f;
    float sum = p2;
    #pragma unroll
    for (int off = 32; off > 0; off >>= 1) sum += __shfl_xor(sum, off);
    if (act) out[(size_t)nd * 40 + lane] = o - mx - __logf(sum);
}

// ---------------------------------------------------------------------------
extern "C" void kernel_launch(void* const* d_in, const int* in_sizes, int n_in,
                              void* d_out, int out_size, void* d_ws, size_t ws_size,
                              hipStream_t stream) {
    const float* features = (const float*)d_in[0];
    const int*   src      = (const int*)d_in[1];
    const int*   dst      = (const int*)d_in[2];
    const float* W1  = (const float*)d_in[3];
    const float* al1 = (const float*)d_in[4];
    const float* ar1 = (const float*)d_in[5];
    const float* b1  = (const float*)d_in[6];
    const float* W2  = (const float*)d_in[7];
    const float* al2 = (const float*)d_in[8];
    const float* ar2 = (const float*)d_in[9];
    const float* b2  = (const float*)d_in[10];
    const float* W3  = (const float*)d_in[11];
    const float* al3 = (const float*)d_in[12];
    const float* ar3 = (const float*)d_in[13];
    const float* b3  = (const float*)d_in[14];
    float* out = (float*)d_out;

    const int N = NNODES, E = NEDGES;
    const int NGH = 256 * NSB;         // 64000 hist entries
    const int NBG = (NGH + 255) / 256; // 250 scan blocks

    // workspace layout (bytes)
    char* ws = (char*)d_ws;
    __bf16* z40    = (__bf16*)(ws + 0);            // N*64*2 (layer 3)
    __bf16* Wt3    = (__bf16*)(ws + 6400000);      // 48*128*2
    unsigned* keysB = (unsigned*)(ws + 8000000);   // E*4 (sort ping)
    int* gh        = (int*)(ws + 12000000);        // 64000*4
    int* ghs       = (int*)(ws + 12400000);        // 64000*4
    int* bsum      = (int*)(ws + 12700000);        // 256*4
    __bf16* zb     = (__bf16*)(ws + 25600000);     // N*128*2
    __bf16* hb     = (__bf16*)(ws + 38400000);     // N*128*2
    float*  elb    = (float*)(ws + 51200000);      // N*4*4
    float*  erb    = (float*)(ws + 52000000);      // N*4*4
    __bf16* Wt1    = (__bf16*)(ws + 52800000);     // 128*256*2
    __bf16* Wt2    = (__bf16*)(ws + 52865536);     // 128*128*2
    int* row_ptr   = (int*)(ws + 52898304);        // (N+1)*4
    unsigned* keysA = (unsigned*)(ws + 53299520);  // E*4 (ends 56,499,520)
    ushort* csr16  = (ushort*)(ws + 56499520);     // E*2 -> ends 58,099,520

    // ---- prep + sort hist (1 launch) ----
    k_prep_hist<<<216 + NSB, 256, 0, stream>>>(W1, W2, W3, Wt1, Wt2, Wt3,
                                               src, dst, keysA, gh, E);
    // ---- scans + bucket sort ----
    k_scan1<<<NBG, 256, 0, stream>>>(gh, ghs, bsum, NGH);
    k_scan3b<<<NBG, 256, 0, stream>>>(ghs, bsum, NBG, NGH);
    rs_scatter1<<<NSB, 256, 0, stream>>>(keysA, keysB, ghs, E);
    rs_bucket<<<256, 256, 0, stream>>>(keysB, ghs, csr16, row_ptr, E);

    // ---- layer 1 ----
    gemm_mfma_128<true><<<(N + 63) / 64, 256, 0, stream>>>(features, Wt1, al1, ar1, zb, elb, erb, N, 256);
    gat_agg128w<<<(N + 3) / 4, 256, 0, stream>>>(zb, elb, erb, row_ptr, csr16, b1, hb, N);

    // ---- layer 2 ----
    gemm_mfma_128<false><<<(N + 63) / 64, 256, 0, stream>>>(hb, Wt2, al2, ar2, zb, elb, erb, N, 128);
    gat_agg128w<<<(N + 3) / 4, 256, 0, stream>>>(zb, elb, erb, row_ptr, csr16, b2, hb, N);

    // ---- layer 3 ----
    gemm40_mfma<<<(N + 63) / 64, 256, 0, stream>>>(hb, Wt3, al3, ar3, z40, elb, erb, N);
    gat_agg40c<<<(N + 3) / 4, 256, 0, stream>>>(z40, elb, erb, row_ptr, csr16, b3, out, N);

    (void)in_sizes; (void)n_in; (void)out_size; (void)ws_size;
}

// Round 14
// 178.490 us; speedup vs baseline: 1.0419x; 1.0419x over previous
//
#include <hip/hip_runtime.h>
#include <hip/hip_bf16.h>
#include <math.h>

// Problem constants (GAT_66907000537778)
#define NNODES 50000
#define NEDGES 800000
#define FIN 256
#define HID 32
#define HEADS 4
#define OUTS 40
#define HIDDEN 128   // HEADS*HID
#define CH 3200      // edges per sort block (250 * 3200 = 800000 exactly)
#define NSB 250      // sort blocks

typedef __bf16 bf16x8 __attribute__((ext_vector_type(8)));
typedef float  f32x4  __attribute__((ext_vector_type(4)));

// ---------------------------------------------------------------------------
// fused prep (weight converts, blocks 0..215) + sort hist (blocks 216..465)
// ---------------------------------------------------------------------------
__global__ __launch_bounds__(256) void k_prep_hist(
    const float* __restrict__ W1, const float* __restrict__ W2,
    const float* __restrict__ W3, __bf16* __restrict__ Wt1,
    __bf16* __restrict__ Wt2, __bf16* __restrict__ Wt3,
    const int* __restrict__ src, const int* __restrict__ dst,
    unsigned* __restrict__ keysA, int* __restrict__ gh, int n) {
    __shared__ int lh[256];
    int b = blockIdx.x, t = threadIdx.x;
    if (b < 128) {                 // W1 [256][128] -> Wt1 [128][256]
        int i = b * 256 + t;
        int k = i >> 7, c = i & 127;
        Wt1[(size_t)c * 256 + k] = (__bf16)W1[i];
    } else if (b < 192) {          // W2 [128][128] -> Wt2 [128][128]
        int i = (b - 128) * 256 + t;
        int k = i >> 7, c = i & 127;
        Wt2[(size_t)c * 128 + k] = (__bf16)W2[i];
    } else if (b < 216) {          // W3 [128][40] -> Wt3 [48][128], rows 40..47 zero
        int i = (b - 192) * 256 + t;
        int c = i >> 7, k = i & 127;
        Wt3[(size_t)c * 128 + k] = (c < 40) ? (__bf16)W3[(size_t)k * 40 + c] : (__bf16)0.f;
    } else {                       // sort stage 1: pack keys + per-(bin,block) hist
        int sb = b - 216;
        lh[t] = 0;
        __syncthreads();
        int i0 = sb * CH, i1 = i0 + CH; if (i1 > n) i1 = n;
        for (int i = i0 + t; i < i1; i += 256) {
            int d = dst[i];
            keysA[i] = ((unsigned)d << 16) | (unsigned)(src[i] & 0xffff);
            atomicAdd(&lh[d >> 8], 1);
        }
        __syncthreads();
        gh[t * NSB + sb] = lh[t];  // bin-major layout
    }
}

// ---------------------------------------------------------------------------
// scans: stage1 per-block excl scan; stage2+3 merged (redundant bsum scan)
// ---------------------------------------------------------------------------
__global__ __launch_bounds__(256) void k_scan1(const int* __restrict__ counts,
                                               int* __restrict__ pre,
                                               int* __restrict__ bsum, int n) {
    __shared__ int ws[4];
    int t = threadIdx.x, b = blockIdx.x, i = b * 256 + t;
    int lane = t & 63, w = t >> 6;
    int v = (i < n) ? counts[i] : 0;
    int x = v;
    #pragma unroll
    for (int off = 1; off < 64; off <<= 1) {
        int tt = __shfl_up(x, off);
        if (lane >= off) x += tt;
    }
    if (lane == 63) ws[w] = x;
    __syncthreads();
    int woff = 0;
    #pragma unroll
    for (int k = 0; k < 4; ++k) woff += (k < w) ? ws[k] : 0;
    int excl = x - v + woff;
    if (i < n) pre[i] = excl;
    if (t == 255) bsum[b] = excl + v;
}

__global__ __launch_bounds__(256) void k_scan3b(int* __restrict__ ghs,
                                                const int* __restrict__ bsum,
                                                int nb, int n) {
    __shared__ int arr[256];
    __shared__ int ws[4];
    int t = threadIdx.x, b = blockIdx.x;
    int lane = t & 63, w = t >> 6;
    int v = (t < nb) ? bsum[t] : 0;
    int x = v;
    #pragma unroll
    for (int off = 1; off < 64; off <<= 1) {
        int tt = __shfl_up(x, off);
        if (lane >= off) x += tt;
    }
    if (lane == 63) ws[w] = x;
    __syncthreads();
    int woff = 0;
    #pragma unroll
    for (int k = 0; k < 4; ++k) woff += (k < w) ? ws[k] : 0;
    arr[t] = x - v + woff;   // exclusive prefix of bsum
    __syncthreads();
    int sx = arr[b];
    int i = b * 256 + t;
    if (i < n) ghs[i] += sx;
}

// scatter into contiguous bucket regions (order within bucket free)
__global__ __launch_bounds__(256) void rs_scatter1(
    const unsigned* __restrict__ keysA, unsigned* __restrict__ keysB,
    const int* __restrict__ ghs, int n) {
    __shared__ int base[256];
    int t = threadIdx.x, b = blockIdx.x;
    base[t] = ghs[t * NSB + b];
    __syncthreads();
    int i0 = b * CH, i1 = i0 + CH; if (i1 > n) i1 = n;
    for (int i = i0 + t; i < i1; i += 256) {
        unsigned v = keysA[i];
        int bin = v >> 24;           // dst >> 8
        int pos = atomicAdd(&base[bin], 1);
        keysB[pos] = v;
    }
}

// per-bucket counting sort -> row_ptr + csr16 (one block per bucket)
__global__ __launch_bounds__(256) void rs_bucket(
    const unsigned* __restrict__ keysB, const int* __restrict__ ghs,
    ushort* __restrict__ csr16, int* __restrict__ rp, int n) {
    __shared__ int cnt[256];
    __shared__ int ws[4];
    int t = threadIdx.x, hb = blockIdx.x;
    int start = ghs[hb * NSB];
    int end = (hb == 255) ? n : ghs[(hb + 1) * NSB];
    cnt[t] = 0;
    __syncthreads();
    for (int i = start + t; i < end; i += 256)
        atomicAdd(&cnt[(keysB[i] >> 16) & 255], 1);
    __syncthreads();
    int lane = t & 63, w = t >> 6;
    int v = cnt[t];
    int x = v;
    #pragma unroll
    for (int off = 1; off < 64; off <<= 1) {
        int tt = __shfl_up(x, off);
        if (lane >= off) x += tt;
    }
    if (lane == 63) ws[w] = x;
    __syncthreads();
    int woff = 0;
    #pragma unroll
    for (int k = 0; k < 4; ++k) woff += (k < w) ? ws[k] : 0;
    int excl = x - v + woff;
    int node = hb * 256 + t;
    if (node <= NNODES) rp[node] = start + excl;
    __syncthreads();
    cnt[t] = excl;
    __syncthreads();
    for (int i = start + t; i < end; i += 256) {
        unsigned v2 = keysB[i];
        int j = (v2 >> 16) & 255;
        int pos = start + atomicAdd(&cnt[j], 1);
        csr16[pos] = (ushort)(v2 & 0xffffu);
    }
}

// ---------------------------------------------------------------------------
// MFMA bf16 GEMM, N=128, fused attention-score epilogue.
// AF32: A is fp32 (converted during LDS staging); else bf16.
// ---------------------------------------------------------------------------
template<bool AF32>
__global__ __launch_bounds__(256) void gemm_mfma_128(
    const void* __restrict__ Av, const __bf16* __restrict__ Wt,
    const float* __restrict__ al, const float* __restrict__ ar,
    __bf16* __restrict__ z, float* __restrict__ el, float* __restrict__ er,
    int M, int K)
{
    __shared__ alignas(16) __bf16 As[64 * 40];
    __shared__ alignas(16) __bf16 Bs[128 * 40];
    int tid = threadIdx.x;
    int wv = tid >> 6, l = tid & 63;
    int lr = l & 15, lk = l >> 4;
    int m0 = blockIdx.x * 64;
    f32x4 acc[8];
    f32x4 zero4 = {0.f, 0.f, 0.f, 0.f};
    #pragma unroll
    for (int nt = 0; nt < 8; ++nt) acc[nt] = zero4;

    int ar_ = tid >> 2, aq = tid & 3;
    for (int k0 = 0; k0 < K; k0 += 32) {
        {   // A tile: 64 x 32 bf16
            int m = m0 + ar_;
            if constexpr (AF32) {
                const float* A = (const float*)Av;
                __bf16 t8[8] = {};
                if (m < M) {
                    const float4* p = reinterpret_cast<const float4*>(&A[(size_t)m * K + k0 + aq * 8]);
                    float4 a = p[0], b = p[1];
                    t8[0] = (__bf16)a.x; t8[1] = (__bf16)a.y; t8[2] = (__bf16)a.z; t8[3] = (__bf16)a.w;
                    t8[4] = (__bf16)b.x; t8[5] = (__bf16)b.y; t8[6] = (__bf16)b.z; t8[7] = (__bf16)b.w;
                }
                *reinterpret_cast<uint4*>(&As[ar_ * 40 + aq * 8]) = *reinterpret_cast<uint4*>(t8);
            } else {
                const __bf16* A = (const __bf16*)Av;
                uint4 av = make_uint4(0, 0, 0, 0);
                if (m < M) av = *reinterpret_cast<const uint4*>(&A[(size_t)m * K + k0 + aq * 8]);
                *reinterpret_cast<uint4*>(&As[ar_ * 40 + aq * 8]) = av;
            }
        }
        {   // B tile: Wt rows (col-major W): 128 x 32 bf16
            #pragma unroll
            for (int t = 0; t < 2; ++t) {
                int cid = tid + t * 256;
                int c = cid >> 2, q = cid & 3;
                *reinterpret_cast<uint4*>(&Bs[c * 40 + q * 8]) =
                    *reinterpret_cast<const uint4*>(&Wt[(size_t)c * K + k0 + q * 8]);
            }
        }
        __syncthreads();
        bf16x8 af = *reinterpret_cast<const bf16x8*>(&As[(wv * 16 + lr) * 40 + lk * 8]);
        #pragma unroll
        for (int nt = 0; nt < 8; ++nt) {
            bf16x8 bfr = *reinterpret_cast<const bf16x8*>(&Bs[(nt * 16 + lr) * 40 + lk * 8]);
            acc[nt] = __builtin_amdgcn_mfma_f32_16x16x32_bf16(af, bfr, acc[nt], 0, 0, 0);
        }
        __syncthreads();
    }

    float alv[8], arv[8];
    #pragma unroll
    for (int nt = 0; nt < 8; ++nt) {
        alv[nt] = al[nt * 16 + lr];
        arv[nt] = ar[nt * 16 + lr];
    }
    #pragma unroll
    for (int r = 0; r < 4; ++r) {
        int m = m0 + wv * 16 + lk * 4 + r;   // C/D: row=(lane>>4)*4+reg, col=lane&15
        float pel[4], per_[4];
        #pragma unroll
        for (int h = 0; h < 4; ++h) {
            pel[h]  = acc[2 * h][r] * alv[2 * h] + acc[2 * h + 1][r] * alv[2 * h + 1];
            per_[h] = acc[2 * h][r] * arv[2 * h] + acc[2 * h + 1][r] * arv[2 * h + 1];
        }
        #pragma unroll
        for (int mk = 1; mk < 16; mk <<= 1) {
            #pragma unroll
            for (int h = 0; h < 4; ++h) {
                pel[h]  += __shfl_xor(pel[h], mk);
                per_[h] += __shfl_xor(per_[h], mk);
            }
        }
        if (m < M) {
            #pragma unroll
            for (int nt = 0; nt < 8; ++nt)
                z[(size_t)m * 128 + nt * 16 + lr] = (__bf16)acc[nt][r];
            if (lr == 0) {
                #pragma unroll
                for (int h = 0; h < 4; ++h) {
                    el[m * 4 + h] = pel[h];
                    er[m * 4 + h] = per_[h];
                }
            }
        }
    }
}

// ---------------------------------------------------------------------------
// layer-3 MFMA GEMM: z40[M,40(pad64)] = A[M,128] * W3[128,40], fused el3/er3.
// ---------------------------------------------------------------------------
__global__ __launch_bounds__(256) void gemm40_mfma(
    const __bf16* __restrict__ A, const __bf16* __restrict__ Wt3,
    const float* __restrict__ al, const float* __restrict__ arr,
    __bf16* __restrict__ z40, float* __restrict__ el3, float* __restrict__ er3,
    int M)
{
    __shared__ alignas(16) __bf16 As[64 * 40];
    __shared__ alignas(16) __bf16 Bs[48 * 40];
    int tid = threadIdx.x;
    int wv = tid >> 6, l = tid & 63;
    int lr = l & 15, lk = l >> 4;
    int m0 = blockIdx.x * 64;
    f32x4 acc[3];
    f32x4 zero4 = {0.f, 0.f, 0.f, 0.f};
    #pragma unroll
    for (int nt = 0; nt < 3; ++nt) acc[nt] = zero4;

    int ar_ = tid >> 2, aq = tid & 3;
    for (int k0 = 0; k0 < 128; k0 += 32) {
        {
            int m = m0 + ar_;
            uint4 av = make_uint4(0, 0, 0, 0);
            if (m < M) av = *reinterpret_cast<const uint4*>(&A[(size_t)m * 128 + k0 + aq * 8]);
            *reinterpret_cast<uint4*>(&As[ar_ * 40 + aq * 8]) = av;
        }
        if (tid < 192) {
            int c = tid >> 2, q = tid & 3;
            *reinterpret_cast<uint4*>(&Bs[c * 40 + q * 8]) =
                *reinterpret_cast<const uint4*>(&Wt3[(size_t)c * 128 + k0 + q * 8]);
        }
        __syncthreads();
        bf16x8 af = *reinterpret_cast<const bf16x8*>(&As[(wv * 16 + lr) * 40 + lk * 8]);
        #pragma unroll
        for (int nt = 0; nt < 3; ++nt) {
            bf16x8 bfr = *reinterpret_cast<const bf16x8*>(&Bs[(nt * 16 + lr) * 40 + lk * 8]);
            acc[nt] = __builtin_amdgcn_mfma_f32_16x16x32_bf16(af, bfr, acc[nt], 0, 0, 0);
        }
        __syncthreads();
    }

    float alv[3], arv[3];
    #pragma unroll
    for (int nt = 0; nt < 3; ++nt) {
        int col = nt * 16 + lr;
        alv[nt] = (col < 40) ? al[col] : 0.f;
        arv[nt] = (col < 40) ? arr[col] : 0.f;
    }
    #pragma unroll
    for (int r = 0; r < 4; ++r) {
        int m = m0 + wv * 16 + lk * 4 + r;
        float pel = acc[0][r] * alv[0] + acc[1][r] * alv[1] + acc[2][r] * alv[2];
        float per_ = acc[0][r] * arv[0] + acc[1][r] * arv[1] + acc[2][r] * arv[2];
        #pragma unroll
        for (int mk = 1; mk < 16; mk <<= 1) {
            pel  += __shfl_xor(pel, mk);
            per_ += __shfl_xor(per_, mk);
        }
        if (m < M) {
            #pragma unroll
            for (int nt = 0; nt < 3; ++nt) {
                int col = nt * 16 + lr;
                if (col < 40) z40[(size_t)m * 64 + col] = (__bf16)acc[nt][r];
            }
            if (lr == 0) { el3[m] = pel; er3[m] = per_; }
        }
    }
}

// ---------------------------------------------------------------------------
// edge-softmax + aggregation, layers 1-2 (H=4, F=32). One wave per node.
// ---------------------------------------------------------------------------
__global__ __launch_bounds__(256) void gat_agg128w(
    const __bf16* __restrict__ z, const float* __restrict__ el,
    const float* __restrict__ er, const int* __restrict__ rp,
    const ushort* __restrict__ cs, const float* __restrict__ bias,
    __bf16* __restrict__ hout, int n_nodes)
{
    __shared__ uint2 sh[4][4][16];   // [wave][group][edge] = {row elem offset, p}
    int tid = threadIdx.x, w = tid >> 6, t = tid & 63;
    int g = t >> 4, j = t & 15;
    int nd = blockIdx.x * 4 + w;
    if (nd >= n_nodes) return;
    int beg = rp[nd], end = rp[nd + 1];
    float erv = er[nd * 4 + g];
    float m = -3.0e38f, s = 0.f, acc0 = 0.f, acc1 = 0.f;
    const int eoff = g * 32 + 2 * j;

    for (int c0 = beg; c0 < end; c0 += 16) {
        int ch = end - c0; if (ch > 16) ch = 16;
        int chp = (ch + 7) & ~7;
        // ---- phase 1: 16 edge scores per head group ----
        int sidx = (j < ch) ? (int)cs[c0 + j] : 0;
        float e = -3.0e38f;
        if (j < ch) {
            float ev = el[sidx * 4 + g] + erv;
            e = (ev > 0.f) ? ev : 0.2f * ev;
        }
        float cm = e;
        #pragma unroll
        for (int mk = 8; mk; mk >>= 1) cm = fmaxf(cm, __shfl_xor(cm, mk));
        float nm = fmaxf(m, cm);
        float p = (j < ch) ? __expf(e - nm) : 0.f;
        float ps = p;
        #pragma unroll
        for (int mk = 8; mk; mk >>= 1) ps += __shfl_xor(ps, mk);
        float so = __expf(m - nm);
        s = s * so + ps;
        acc0 *= so; acc1 *= so;
        m = nm;
        sh[w][g][j] = make_uint2((unsigned)(sidx << 7), __float_as_uint(p));
        // intra-wave LDS: each group reads only what it wrote -> no barrier
        // ---- phase 2: 8-deep dword gathers (2 bf16 each) ----
        for (int k = 0; k < chp; k += 8) {
            unsigned ld[8]; float pk[8];
            #pragma unroll
            for (int u = 0; u < 8; ++u) {
                uint2 v = sh[w][g][k + u];
                pk[u] = __uint_as_float(v.y);
                ld[u] = *reinterpret_cast<const unsigned*>(&z[(size_t)v.x + eoff]);
            }
            #pragma unroll
            for (int u = 0; u < 8; ++u) {
                float z0 = __uint_as_float(ld[u] << 16);
                float z1 = __uint_as_float(ld[u] & 0xffff0000u);
                acc0 += pk[u] * z0;
                acc1 += pk[u] * z1;
            }
        }
    }
    float o0 = (end > beg) ? acc0 / s : 0.f;
    float o1 = (end > beg) ? acc1 / s : 0.f;
    o0 = fmaxf(o0 + bias[eoff], 0.f);       // relu (layers 1-2)
    o1 = fmaxf(o1 + bias[eoff + 1], 0.f);
    __bf16 t2[2] = {(__bf16)o0, (__bf16)o1};
    *reinterpret_cast<unsigned*>(&hout[(size_t)nd * 128 + eoff]) = *reinterpret_cast<unsigned*>(t2);
}

// ---------------------------------------------------------------------------
// layer-3 aggregation: chunk-parallel, 1 node per wave, + bias + log_softmax
// ---------------------------------------------------------------------------
__global__ __launch_bounds__(256) void gat_agg40c(
    const __bf16* __restrict__ z40, const float* __restrict__ el3,
    const float* __restrict__ er3, const int* __restrict__ rp,
    const ushort* __restrict__ cs, const float* __restrict__ bias,
    float* __restrict__ out, int n_nodes)
{
    __shared__ uint2 sh[4][64];
    int tid = threadIdx.x, wid = tid >> 6, lane = tid & 63;
    int nd = blockIdx.x * 4 + wid;
    if (nd >= n_nodes) return;
    bool act = lane < 40;
    int beg = rp[nd], end = rp[nd + 1];
    float erv = er3[nd];
    float m = -3.0e38f, s = 0.f, acc = 0.f;

    for (int c0 = beg; c0 < end; c0 += 64) {
        int ch = end - c0; if (ch > 64) ch = 64;
        int chp = (ch + 7) & ~7;
        int sidx = (lane < ch) ? (int)cs[c0 + lane] : 0;
        float e = -3.0e38f;
        if (lane < ch) {
            float ev = el3[sidx] + erv;
            e = (ev > 0.f) ? ev : 0.2f * ev;
        }
        float cm = e;
        #pragma unroll
        for (int mk = 32; mk; mk >>= 1) cm = fmaxf(cm, __shfl_xor(cm, mk));
        float nm = fmaxf(m, cm);
        float p = (lane < ch) ? __expf(e - nm) : 0.f;
        float ps = p;
        #pragma unroll
        for (int mk = 32; mk; mk >>= 1) ps += __shfl_xor(ps, mk);
        float so = __expf(m - nm);
        s = s * so + ps;
        acc *= so;
        m = nm;
        sh[wid][lane] = make_uint2((unsigned)(sidx << 6), __float_as_uint(p));
        for (int k = 0; k < chp; k += 8) {
            float zv[8], pk[8];
            #pragma unroll
            for (int u = 0; u < 8; ++u) {
                uint2 v = sh[wid][k + u];
                pk[u] = __uint_as_float(v.y);
                zv[u] = (float)z40[(size_t)v.x + lane];
            }
            #pragma unroll
            for (int u = 0; u < 8; ++u) acc += pk[u] * zv[u];
        }
    }
    float o = (end > beg) ? acc / s : 0.f;
    o += act ? bias[lane] : 0.f;
    float v = act ? o : -3.0e38f;
    float mx = v;
    #pragma unroll
    for (int off = 32; off > 0; off >>= 1) mx = fmaxf(mx, __shfl_xor(mx, off));
    float p2 = act ? __expf(o - mx) : 0.f;
    float sum = p2;
    #pragma unroll
    for (int off = 32; off > 0; off >>= 1) sum += __shfl_xor(sum, off);
    if (act) out[(size_t)nd * 40 + lane] = o - mx - __logf(sum);
}

// ---------------------------------------------------------------------------
extern "C" void kernel_launch(void* const* d_in, const int* in_sizes, int n_in,
                              void* d_out, int out_size, void* d_ws, size_t ws_size,
                              hipStream_t stream) {
    const float* features = (const float*)d_in[0];
    const int*   src      = (const int*)d_in[1];
    const int*   dst      = (const int*)d_in[2];
    const float* W1  = (const float*)d_in[3];
    const float* al1 = (const float*)d_in[4];
    const float* ar1 = (const float*)d_in[5];
    const float* b1  = (const float*)d_in[6];
    const float* W2  = (const float*)d_in[7];
    const float* al2 = (const float*)d_in[8];
    const float* ar2 = (const float*)d_in[9];
    const float* b2  = (const float*)d_in[10];
    const float* W3  = (const float*)d_in[11];
    const float* al3 = (const float*)d_in[12];
    const float* ar3 = (const float*)d_in[13];
    const float* b3  = (const float*)d_in[14];
    float* out = (float*)d_out;

    const int N = NNODES, E = NEDGES;
    const int NGH = 256 * NSB;         // 64000 hist entries
    const int NBG = (NGH + 255) / 256; // 250 scan blocks

    // workspace layout (bytes)
    char* ws = (char*)d_ws;
    __bf16* z40    = (__bf16*)(ws + 0);            // N*64*2 (layer 3)
    __bf16* Wt3    = (__bf16*)(ws + 6400000);      // 48*128*2
    unsigned* keysB = (unsigned*)(ws + 8000000);   // E*4 (sort ping)
    int* gh        = (int*)(ws + 12000000);        // 64000*4
    int* ghs       = (int*)(ws + 12400000);        // 64000*4
    int* bsum      = (int*)(ws + 12700000);        // 256*4
    __bf16* zb     = (__bf16*)(ws + 25600000);     // N*128*2
    __bf16* hb     = (__bf16*)(ws + 38400000);     // N*128*2
    float*  elb    = (float*)(ws + 51200000);      // N*4*4
    float*  erb    = (float*)(ws + 52000000);      // N*4*4
    __bf16* Wt1    = (__bf16*)(ws + 52800000);     // 128*256*2
    __bf16* Wt2    = (__bf16*)(ws + 52865536);     // 128*128*2
    int* row_ptr   = (int*)(ws + 52898304);        // (N+1)*4
    unsigned* keysA = (unsigned*)(ws + 53299520);  // E*4 (ends 56,499,520)
    ushort* csr16  = (ushort*)(ws + 56499520);     // E*2 -> ends 58,099,520

    // ---- prep + sort hist (1 launch) ----
    k_prep_hist<<<216 + NSB, 256, 0, stream>>>(W1, W2, W3, Wt1, Wt2, Wt3,
                                               src, dst, keysA, gh, E);
    // ---- scans + bucket sort ----
    k_scan1<<<NBG, 256, 0, stream>>>(gh, ghs, bsum, NGH);
    k_scan3b<<<NBG, 256, 0, stream>>>(ghs, bsum, NBG, NGH);
    rs_scatter1<<<NSB, 256, 0, stream>>>(keysA, keysB, ghs, E);
    rs_bucket<<<256, 256, 0, stream>>>(keysB, ghs, csr16, row_ptr, E);

    // ---- layer 1 ----
    gemm_mfma_128<true><<<(N + 63) / 64, 256, 0, stream>>>(features, Wt1, al1, ar1, zb, elb, erb, N, 256);
    gat_agg128w<<<(N + 3) / 4, 256, 0, stream>>>(zb, elb, erb, row_ptr, csr16, b1, hb, N);

    // ---- layer 2 ----
    gemm_mfma_128<false><<<(N + 63) / 64, 256, 0, stream>>>(hb, Wt2, al2, ar2, zb, elb, erb, N, 128);
    gat_agg128w<<<(N + 3) / 4, 256, 0, stream>>>(zb, elb, erb, row_ptr, csr16, b2, hb, N);

    // ---- layer 3 ----
    gemm40_mfma<<<(N + 63) / 64, 256, 0, stream>>>(hb, Wt3, al3, ar3, z40, elb, erb, N);
    gat_agg40c<<<(N + 3) / 4, 256, 0, stream>>>(z40, elb, erb, row_ptr, csr16, b3, out, N);

    (void)in_sizes; (void)n_in; (void)out_size; (void)ws_size;
}